// Round 1
// baseline (495.865 us; speedup 1.0000x reference)
//
#include <hip/hip_runtime.h>
#include <hip/hip_bf16.h>
#include <math.h>

#define L_SEQ 4096
#define DIM   1024
#define NH    16
#define HD    64

typedef __attribute__((ext_vector_type(4))) float f32x4;
typedef __attribute__((ext_vector_type(8))) short s16x8;
typedef __attribute__((ext_vector_type(4))) short s16x4;

__device__ __forceinline__ short f2bf(float f) {
  unsigned u = __builtin_bit_cast(unsigned, f);
  u = u + 0x7fffu + ((u >> 16) & 1u);   // RNE
  return (short)(u >> 16);
}

__device__ __forceinline__ void gload_lds16(const void* g, void* l) {
  __builtin_amdgcn_global_load_lds(
      (__attribute__((address_space(1))) void*)(g),
      (__attribute__((address_space(3))) void*)(l), 16, 0, 0);
}

// ---------------- fp32 -> bf16 convert ----------------
__global__ __launch_bounds__(256) void cvt_f32_bf16(const float* __restrict__ src,
                                                    short* __restrict__ dst, int n4) {
  int i = blockIdx.x * 256 + threadIdx.x;
  if (i >= n4) return;
  f32x4 f = *(const f32x4*)(src + i * 4);
  s16x4 o;
  o[0] = f2bf(f[0]); o[1] = f2bf(f[1]); o[2] = f2bf(f[2]); o[3] = f2bf(f[3]);
  *(s16x4*)(dst + i * 4) = o;
}

// ---------------- GEMM: C = A(bf16)[M,K] * B(bf16)[N,K]^T + bias ----------------
// 128x128 tile, 4 waves (2x2 of 64x64), BK=32, mfma_f32_16x16x32_bf16.
// A-frag: lane holds A[row=l%16][k=(l/16)*8 + 0..7]; B-frag: B[col=l%16][k=(l/16)*8+0..7]
// C-frag: col = l&15, row = (l>>4)*4 + reg   (m89-verified)

#define GEMM_MAINLOOP(A_, B_, Kdim)                                            \
  f32x4 acc[4][4];                                                             \
  _Pragma("unroll") for (int m = 0; m < 4; ++m)                                \
  _Pragma("unroll") for (int n = 0; n < 4; ++n) acc[m][n] = (f32x4)0.f;        \
  const short* aptr = A_ + (bm * 128 + w * 16 + (l >> 2)) * (Kdim) + (l & 3) * 8; \
  const short* bptr = B_ + (bn * 128 + w * 16 + (l >> 2)) * (Kdim) + (l & 3) * 8; \
  short* asl = &As[(w * 16) * 32];                                             \
  short* bsl = &Bs[(w * 16) * 32];                                             \
  for (int kk = 0; kk < (Kdim); kk += 32) {                                    \
    gload_lds16(aptr + kk, asl);                                               \
    gload_lds16(aptr + kk + 64 * (Kdim), asl + 64 * 32);                       \
    gload_lds16(bptr + kk, bsl);                                               \
    gload_lds16(bptr + kk + 64 * (Kdim), bsl + 64 * 32);                       \
    __syncthreads();                                                           \
    s16x8 af[4], bfr[4];                                                       \
    _Pragma("unroll") for (int m = 0; m < 4; ++m)                              \
      af[m] = *(const s16x8*)&As[(wr * 64 + m * 16 + lr) * 32 + lg * 8];       \
    _Pragma("unroll") for (int n = 0; n < 4; ++n)                              \
      bfr[n] = *(const s16x8*)&Bs[(wc * 64 + n * 16 + lr) * 32 + lg * 8];      \
    _Pragma("unroll") for (int m = 0; m < 4; ++m)                              \
    _Pragma("unroll") for (int n = 0; n < 4; ++n)                              \
      acc[m][n] = __builtin_amdgcn_mfma_f32_16x16x32_bf16(af[m], bfr[n], acc[m][n], 0, 0, 0); \
    __syncthreads();                                                           \
  }

__global__ __launch_bounds__(256) void gemm_qkv(const short* __restrict__ A,
                                                const short* __restrict__ B,
                                                const float* __restrict__ bias,
                                                short* __restrict__ Qb,
                                                short* __restrict__ Kb,
                                                short* __restrict__ Vb) {
  __shared__ __align__(16) short As[128 * 32];
  __shared__ __align__(16) short Bs[128 * 32];
  const int t = threadIdx.x;
  const int w = t >> 6, l = t & 63;
  const int wr = w >> 1, wc = w & 1;
  const int lr = l & 15, lg = l >> 4;
  const int bm = blockIdx.x, bn = blockIdx.y;

  GEMM_MAINLOOP(A, B, DIM)

  const int row0 = bm * 128 + wr * 64;
  const int col0 = bn * 128 + wc * 64;
#pragma unroll
  for (int n = 0; n < 4; ++n) {
    const int col = col0 + n * 16 + lr;
    const float bv = bias[col];
    const int which = col >> 10;
    const int head = (col & 1023) >> 6;
    const int d = col & 63;
    short* dst = (which == 0) ? Qb : ((which == 1) ? Kb : Vb);
    dst += (head * L_SEQ) * HD + d;
#pragma unroll
    for (int m = 0; m < 4; ++m)
#pragma unroll
      for (int j = 0; j < 4; ++j) {
        const int row = row0 + m * 16 + lg * 4 + j;
        dst[row * HD] = f2bf(acc[m][n][j] + bv);
      }
  }
}

__global__ __launch_bounds__(256) void gemm_out(const short* __restrict__ A,
                                                const short* __restrict__ B,
                                                const float* __restrict__ bias,
                                                float* __restrict__ C) {
  __shared__ __align__(16) short As[128 * 32];
  __shared__ __align__(16) short Bs[128 * 32];
  const int t = threadIdx.x;
  const int w = t >> 6, l = t & 63;
  const int wr = w >> 1, wc = w & 1;
  const int lr = l & 15, lg = l >> 4;
  const int bm = blockIdx.x, bn = blockIdx.y;

  GEMM_MAINLOOP(A, B, DIM)

  const int row0 = bm * 128 + wr * 64;
  const int col0 = bn * 128 + wc * 64;
#pragma unroll
  for (int n = 0; n < 4; ++n) {
    const int col = col0 + n * 16 + lr;
    const float bv = bias[col];
#pragma unroll
    for (int m = 0; m < 4; ++m)
#pragma unroll
      for (int j = 0; j < 4; ++j) {
        const int row = row0 + m * 16 + lg * 4 + j;
        C[row * DIM + col] = acc[m][n][j] + bv;
      }
  }
}

// ---------------- Flash attention (causal) ----------------
// grid (L/64, NH), 256 threads (4 waves). Wave w owns q rows q0+w*16..+15.
// K frags loaded direct from global (per-head K/V = 512KB, L2-resident).
// V transposed into padded LDS [64][40]; P through per-wave padded LDS.
__global__ __launch_bounds__(256) void attn(const short* __restrict__ Qb,
                                            const short* __restrict__ Kb,
                                            const short* __restrict__ Vb,
                                            short* __restrict__ Ob) {
  __shared__ __align__(16) short VT[64 * 40];
  __shared__ __align__(16) short Pl[4][16 * 40];
  const int qt = blockIdx.x, head = blockIdx.y;
  const int q0 = qt * 64;
  const int t = threadIdx.x, w = t >> 6, l = t & 63;
  const int lr = l & 15, lg = l >> 4;

  const short* Qh = Qb + head * L_SEQ * HD;
  const short* Kh = Kb + head * L_SEQ * HD;
  const short* Vh = Vb + head * L_SEQ * HD;

  const int qrow = q0 + w * 16 + lr;
  const s16x8 qa0 = *(const s16x8*)&Qh[qrow * HD + lg * 8];
  const s16x8 qa1 = *(const s16x8*)&Qh[qrow * HD + 32 + lg * 8];

  f32x4 o[4];
#pragma unroll
  for (int nd = 0; nd < 4; ++nd) o[nd] = (f32x4)0.f;
  float mrow[4] = {-INFINITY, -INFINITY, -INFINITY, -INFINITY};
  float srow[4] = {0.f, 0.f, 0.f, 0.f};

  const int vrow = t >> 3;
  const int vd8 = (t & 7) * 8;
  const int nkt = 2 * qt + 2;
  for (int kt = 0; kt < nkt; ++kt) {
    const int k0 = kt * 32;
    // stage V^T: coalesced 16B read, scalar transpose writes (padded rows)
    {
      s16x8 vv = *(const s16x8*)&Vh[(k0 + vrow) * HD + vd8];
#pragma unroll
      for (int j = 0; j < 8; ++j) VT[(vd8 + j) * 40 + vrow] = vv[j];
    }
    __syncthreads();
    // S = Q K^T  (16q x 32k per wave, two 16-key column blocks)
    f32x4 sacc[2];
    sacc[0] = (f32x4)0.f; sacc[1] = (f32x4)0.f;
#pragma unroll
    for (int kb = 0; kb < 2; ++kb) {
      const s16x8 kf0 = *(const s16x8*)&Kh[(k0 + kb * 16 + lr) * HD + lg * 8];
      const s16x8 kf1 = *(const s16x8*)&Kh[(k0 + kb * 16 + lr) * HD + 32 + lg * 8];
      sacc[kb] = __builtin_amdgcn_mfma_f32_16x16x32_bf16(qa0, kf0, sacc[kb], 0, 0, 0);
      sacc[kb] = __builtin_amdgcn_mfma_f32_16x16x32_bf16(qa1, kf1, sacc[kb], 0, 0, 0);
    }
    // online softmax per C-layout row (lg*4+j), keys k0+kb*16+lr
#pragma unroll
    for (int j = 0; j < 4; ++j) {
      const int row = q0 + w * 16 + lg * 4 + j;
      float s0 = sacc[0][j] * 0.125f;
      float s1 = sacc[1][j] * 0.125f;
      if (k0 + lr > row)      s0 = -INFINITY;
      if (k0 + 16 + lr > row) s1 = -INFINITY;
      float m2 = fmaxf(s0, s1);
#pragma unroll
      for (int off = 1; off < 16; off <<= 1) m2 = fmaxf(m2, __shfl_xor(m2, off, 64));
      const float mn = fmaxf(mrow[j], m2);
      const float mns = (mn == -INFINITY) ? 0.f : mn;   // fully-masked guard
      const float alpha = __expf(mrow[j] - mns);        // -inf -> 0
      mrow[j] = mn;
      const float p0 = __expf(s0 - mns);
      const float p1 = __expf(s1 - mns);
      float ps = p0 + p1;
#pragma unroll
      for (int off = 1; off < 16; off <<= 1) ps += __shfl_xor(ps, off, 64);
      srow[j] = srow[j] * alpha + ps;
      o[0][j] *= alpha; o[1][j] *= alpha; o[2][j] *= alpha; o[3][j] *= alpha;
      Pl[w][(lg * 4 + j) * 40 + lr]      = f2bf(p0);
      Pl[w][(lg * 4 + j) * 40 + 16 + lr] = f2bf(p1);
    }
    // PV: A = P (own-wave LDS), B = V^T rows (shared LDS)
    const s16x8 pa = *(const s16x8*)&Pl[w][lr * 40 + lg * 8];
#pragma unroll
    for (int nd = 0; nd < 4; ++nd) {
      const s16x8 vf = *(const s16x8*)&VT[(nd * 16 + lr) * 40 + lg * 8];
      o[nd] = __builtin_amdgcn_mfma_f32_16x16x32_bf16(pa, vf, o[nd], 0, 0, 0);
    }
    __syncthreads();
  }
  // epilogue: normalize, write bf16 [L][DIM] with col = head*64 + d
#pragma unroll
  for (int j = 0; j < 4; ++j) {
    const float inv = 1.f / srow[j];
    const int row = q0 + w * 16 + lg * 4 + j;
#pragma unroll
    for (int nd = 0; nd < 4; ++nd)
      Ob[row * DIM + head * HD + nd * 16 + lr] = f2bf(o[nd][j] * inv);
  }
}

// ---------------- launch ----------------
extern "C" void kernel_launch(void* const* d_in, const int* in_sizes, int n_in,
                              void* d_out, int out_size, void* d_ws, size_t ws_size,
                              hipStream_t stream) {
  const float* x    = (const float*)d_in[0];
  const float* Wqkv = (const float*)d_in[1];
  const float* bqkv = (const float*)d_in[2];
  const float* Wout = (const float*)d_in[3];
  const float* bout = (const float*)d_in[4];
  float* out = (float*)d_out;

  char* ws = (char*)d_ws;
  short* xb    = (short*)(ws);                    // 8 MB  [L][D] bf16
  short* wqkvb = (short*)(ws + (8u  << 20));      // 6 MB  [3D][D] bf16
  short* woutb = (short*)(ws + (14u << 20));      // 2 MB  [D][D] bf16
  short* Qb    = (short*)(ws + (16u << 20));      // 8 MB  [NH][L][64]
  short* Kb    = (short*)(ws + (24u << 20));      // 8 MB
  short* Vb    = (short*)(ws + (32u << 20));      // 8 MB
  short* Ob    = (short*)(ws + (40u << 20));      // 8 MB  [L][D] bf16

  cvt_f32_bf16<<<(L_SEQ * DIM / 4 + 255) / 256, 256, 0, stream>>>(x, xb, L_SEQ * DIM / 4);
  cvt_f32_bf16<<<(3 * DIM * DIM / 4 + 255) / 256, 256, 0, stream>>>(Wqkv, wqkvb, 3 * DIM * DIM / 4);
  cvt_f32_bf16<<<(DIM * DIM / 4 + 255) / 256, 256, 0, stream>>>(Wout, woutb, DIM * DIM / 4);

  gemm_qkv<<<dim3(L_SEQ / 128, 3 * DIM / 128), 256, 0, stream>>>(xb, wqkvb, bqkv, Qb, Kb, Vb);
  attn<<<dim3(L_SEQ / 64, NH), 256, 0, stream>>>(Qb, Kb, Vb, Ob);
  gemm_out<<<dim3(L_SEQ / 128, DIM / 128), 256, 0, stream>>>(Ob, woutb, bout, out);
}